// Round 3
// baseline (656.443 us; speedup 1.0000x reference)
//
#include <hip/hip_runtime.h>
#include <stdint.h>

// BitInput: bit-exact jax.random.uniform(key(42), [1024,512,256]) via
// partitionable Threefry-2x32 (verified absmax=0 in round 2), thresholded by
// p = inp[flat>>8].
//
//   bits[i] = o0 ^ o1 where (o0,o1) = threefry2x32((0,42), (0, i))
//   out[i]  = ((bits[i] >> 9) < ceil(p * 2^23)) ? 1.0f : 0.0f
//
// Integer-threshold equivalence: u = (bits>>9) * 2^-23 exactly; for integer
// m = bits>>9, m < p*2^23  <=>  m < ceil(p*2^23). p*2^23 and ceilf are exact
// in fp32 (pure exponent shift, p in [0,1)).

__device__ __forceinline__ uint32_t rotl(uint32_t x, uint32_t r) {
    // alignbit(x,x,s) = rotr(x,s); rotl(x,r) = rotr(x, 32-r). One VALU op.
    return __builtin_amdgcn_alignbit(x, x, 32u - r);
}

__device__ __forceinline__ uint32_t tf_bits(uint32_t i) {
    const uint32_t k0 = 0u;
    const uint32_t k1 = 42u;
    const uint32_t k2 = 0x1BD11BDAu ^ k0 ^ k1;   // 0x1BD11BF0
    uint32_t x0 = k0;          // = 0, folds: round-1 add is free
    uint32_t x1 = i + k1;
#define R4(a,b,c,d) \
    x0 += x1; x1 = rotl(x1,(a)); x1 ^= x0; \
    x0 += x1; x1 = rotl(x1,(b)); x1 ^= x0; \
    x0 += x1; x1 = rotl(x1,(c)); x1 ^= x0; \
    x0 += x1; x1 = rotl(x1,(d)); x1 ^= x0;
    R4(13u,15u,26u, 6u)  x0 += k1;      x1 += k2 + 1u;
    R4(17u,29u,16u,24u)  x0 += k2;      x1 += k0 + 2u;
    R4(13u,15u,26u, 6u)  x0 += k0;      x1 += k1 + 3u;
    R4(17u,29u,16u,24u)  x0 += k1;      x1 += k2 + 4u;
    R4(13u,15u,26u, 6u)  x0 += k2;      x1 += k0 + 5u;
#undef R4
    return x0 ^ x1;
}

__global__ __launch_bounds__(256) void bitinput_kernel(
        const float* __restrict__ inp, float* __restrict__ out,
        uint32_t half_n) {
    uint32_t t  = blockIdx.x * blockDim.x + threadIdx.x;
    uint32_t i0 = t * 4u;               // low-half outputs  i0..i0+3
    uint32_t j0 = i0 + half_n;          // high-half outputs j0..j0+3
    if (i0 >= half_n) return;

    // 4 | 256: each group of 4 shares one p. Input is 2 MiB -> L2-resident.
    uint32_t ta = (uint32_t)ceilf(inp[i0 >> 8] * 8388608.0f);  // ceil(p*2^23)
    uint32_t tb = (uint32_t)ceilf(inp[j0 >> 8] * 8388608.0f);

    float4 ra, rb;
    float* pa = reinterpret_cast<float*>(&ra);
    float* pb = reinterpret_cast<float*>(&rb);

#pragma unroll
    for (int k = 0; k < 4; ++k) {
        pa[k] = ((tf_bits(i0 + (uint32_t)k) >> 9) < ta) ? 1.0f : 0.0f;
        pb[k] = ((tf_bits(j0 + (uint32_t)k) >> 9) < tb) ? 1.0f : 0.0f;
    }

    // two perfectly coalesced 16 B/lane stores (low half, high half)
    reinterpret_cast<float4*>(out)[t]           = ra;
    reinterpret_cast<float4*>(out + half_n)[t]  = rb;
}

extern "C" void kernel_launch(void* const* d_in, const int* in_sizes, int n_in,
                              void* d_out, int out_size, void* d_ws, size_t ws_size,
                              hipStream_t stream) {
    const float* inp = (const float*)d_in[0];
    float* out = (float*)d_out;

    uint32_t n = (uint32_t)out_size;        // 2^27
    uint32_t half_n = n >> 1;               // 2^26
    uint32_t threads_needed = half_n >> 2;  // 8 outputs per thread (4 low + 4 high)
    dim3 block(256);
    dim3 grid((threads_needed + block.x - 1) / block.x);
    bitinput_kernel<<<grid, block, 0, stream>>>(inp, out, half_n);
}

// Round 5
// 652.265 us; speedup vs baseline: 1.0064x; 1.0064x over previous
//
#include <hip/hip_runtime.h>
#include <stdint.h>

// BitInput: bit-exact jax.random.uniform(key(42), [1024,512,256]) via
// partitionable Threefry-2x32 (absmax=0 verified round 2/3), thresholded by
// p = inp[flat>>8].
//
//   bits[i] = o0 ^ o1, (o0,o1) = threefry2x32((0,42), (0,i))
//   out[i]  = ((bits[i] >> 9) < ceil(p * 2^23)) ? 1.0f : 0.0f
//
// Round-5 = Round-4 structure with the nontemporal-store type fixed:
// __builtin_nontemporal_store needs a native clang vector, not
// HIP_vector_type — use ext_vector_type(4) float.

typedef float vfloat4 __attribute__((ext_vector_type(4)));

__device__ __forceinline__ uint32_t rotl(uint32_t x, uint32_t r) {
    return __builtin_amdgcn_alignbit(x, x, 32u - r);   // rotr(32-r) = rotl(r)
}

// Two independent Threefry-2x32((0,42)) chains, interleaved statement-by-
// statement so the instruction stream carries ILP=2 regardless of scheduling.
__device__ __forceinline__ void tf_bits2(uint32_t ia, uint32_t ib,
                                         uint32_t& ra, uint32_t& rb) {
    const uint32_t k1 = 42u;
    const uint32_t k2 = 0x1BD11BDAu ^ k1;   // 0x1BD11BF0
    uint32_t a0 = 0u,  a1 = ia + k1;
    uint32_t b0 = 0u,  b1 = ib + k1;
#define RND2(r) \
    a0 += a1; b0 += b1; \
    a1 = rotl(a1,(r)); b1 = rotl(b1,(r)); \
    a1 ^= a0; b1 ^= b0;
#define INJ2(ca,cb) \
    a0 += (ca); b0 += (ca); a1 += (cb); b1 += (cb);
    RND2(13u) RND2(15u) RND2(26u) RND2( 6u)  INJ2(k1,      k2 + 1u)
    RND2(17u) RND2(29u) RND2(16u) RND2(24u)  INJ2(k2,      0u + 2u)
    RND2(13u) RND2(15u) RND2(26u) RND2( 6u)  INJ2(0u,      k1 + 3u)
    RND2(17u) RND2(29u) RND2(16u) RND2(24u)  INJ2(k1,      k2 + 4u)
    RND2(13u) RND2(15u) RND2(26u) RND2( 6u)  INJ2(k2,      0u + 5u)
#undef RND2
#undef INJ2
    ra = a0 ^ a1;
    rb = b0 ^ b1;
}

__global__ __launch_bounds__(256) void bitinput_kernel(
        const float* __restrict__ inp, float* __restrict__ out,
        uint32_t quarter_n) {
    uint32_t t  = blockIdx.x * blockDim.x + threadIdx.x;
    uint32_t i0 = t * 4u;
    if (i0 >= quarter_n) return;

#pragma unroll
    for (int q = 0; q < 4; ++q) {
        uint32_t base = i0 + (uint32_t)q * quarter_n;
        // 4 | 256 and base % 4 == 0: one probability per group of 4.
        // Input is 2 MiB -> L1/L2-resident.
        uint32_t thr = (uint32_t)ceilf(inp[base >> 8] * 8388608.0f);

        uint32_t m0, m1, m2, m3;
        tf_bits2(base + 0u, base + 1u, m0, m1);
        tf_bits2(base + 2u, base + 3u, m2, m3);

        vfloat4 r;
        r.x = ((m0 >> 9) < thr) ? 1.0f : 0.0f;
        r.y = ((m1 >> 9) < thr) ? 1.0f : 0.0f;
        r.z = ((m2 >> 9) < thr) ? 1.0f : 0.0f;
        r.w = ((m3 >> 9) < thr) ? 1.0f : 0.0f;

        // perfectly coalesced 16 B/lane; nontemporal: out is write-once
        __builtin_nontemporal_store(
            r, reinterpret_cast<vfloat4*>(out + base - i0) + t);
    }
}

extern "C" void kernel_launch(void* const* d_in, const int* in_sizes, int n_in,
                              void* d_out, int out_size, void* d_ws, size_t ws_size,
                              hipStream_t stream) {
    const float* inp = (const float*)d_in[0];
    float* out = (float*)d_out;

    uint32_t n = (uint32_t)out_size;          // 2^27
    uint32_t quarter_n = n >> 2;              // 2^25
    uint32_t threads_needed = quarter_n >> 2; // 16 outputs per thread
    dim3 block(256);
    dim3 grid((threads_needed + block.x - 1) / block.x);
    bitinput_kernel<<<grid, block, 0, stream>>>(inp, out, quarter_n);
}